// Round 1
// baseline (310.875 us; speedup 1.0000x reference)
//
#include <hip/hip_runtime.h>

#define N 256
#define NLINE 4               // lines (waves) per block
#define NB (N / NLINE)        // 64 blocks
#define NT (NLINE * 64)       // 256 threads
#define LAM 0.05f             // step = ALPHA/2
#define TWOLAM (2.0f * LAM)
#define FOURLAM (4.0f * LAM)
#define MAXIT 35
#define TOL 0.01f
#define SLOTSTRIDE 4          // uint64 elements -> 32 B per LINE slot; 256 slots = 8 KB (same ws footprint)

// broadcast-read one lane's register (lane index is wave-uniform -> v_readlane)
__device__ __forceinline__ float rlane(float v, int lane) {
    return __int_as_float(__builtin_amdgcn_readlane(__float_as_int(v), lane));
}

// agent-scope (L2-bypassing) scalar access for cross-block-communicated arrays.
__device__ __forceinline__ void gstore(float* p, float v) {
    __hip_atomic_store(p, v, __ATOMIC_RELAXED, __HIP_MEMORY_SCOPE_AGENT);
}
// 16-byte L2-bypassing load (sc0 sc1 = coherent scope, L3-served — never caches
// in L2, so the no-cache-maintenance barrier remains correct).
__device__ __forceinline__ float4 gload4(const float* p) {
    float4 r;
    asm volatile("global_load_dwordx4 %0, %1, off sc0 sc1\n\ts_waitcnt vmcnt(0)"
                 : "=&v"(r) : "v"(p) : "memory");
    return r;
}

// 256-float line distributed over the wave: element k lives in lane (k&63), reg (k>>6)
// -> ballot words are CONTIGUOUS 64-element spans (word w = elements 64w..64w+63)
struct Dist { float r0, r1, r2, r3; };

// branchless fetch: 4 independent readlanes + 2 uniform selects
__device__ __forceinline__ float dfetch(const Dist& d, int k) {
    const int lane = k & 63;
    const int sel = k >> 6;
    float a = rlane(d.r0, lane);
    float b = rlane(d.r1, lane);
    float c = rlane(d.r2, lane);
    float e = rlane(d.r3, lane);
    float ab = (sel & 1) ? b : a;
    float ce = (sel & 1) ? e : c;
    return (sel & 2) ? ce : ab;
}

// O(1) segment flush: o[j] = val for j in [lo, hi]; element j of reg r = 64r + lane
__device__ __forceinline__ void flushseg(Dist& o, int lo, int hi, float val, int lane) {
    const unsigned len = (unsigned)(hi - lo);
    const int base = lane - lo;
    o.r0 = ((unsigned)(base      ) <= len) ? val : o.r0;
    o.r1 = ((unsigned)(base + 64 ) <= len) ? val : o.r1;
    o.r2 = ((unsigned)(base + 128) <= len) ? val : o.r2;
    o.r3 = ((unsigned)(base + 192) <= len) ? val : o.r3;
}

// scalar 4-way select of a 64-bit mask (s_cselect_b64)
__device__ __forceinline__ unsigned long long sel4(unsigned long long a, unsigned long long b,
                                                   unsigned long long c, unsigned long long d, int r) {
    unsigned long long ab = (r & 1) ? b : a;
    unsigned long long cd = (r & 1) ? d : c;
    return (r & 2) ? cd : ab;
}

// full-wave (64-lane) max of a nonneg-float-as-uint via the canonical gfx9 DPP
// ladder (row_shr 1,2,4,8 + row_bcast 15,31 -> lane 63 holds the total).
// VALU-latency chain (~6 ops) instead of 6 serial ds_bpermute (~300 cy).
__device__ __forceinline__ unsigned wredmax(unsigned x) {
    unsigned t;
    t = (unsigned)__builtin_amdgcn_update_dpp(0, (int)x, 0x111, 0xf, 0xf, true); x = x > t ? x : t; // row_shr:1
    t = (unsigned)__builtin_amdgcn_update_dpp(0, (int)x, 0x112, 0xf, 0xf, true); x = x > t ? x : t; // row_shr:2
    t = (unsigned)__builtin_amdgcn_update_dpp(0, (int)x, 0x114, 0xf, 0xf, true); x = x > t ? x : t; // row_shr:4
    t = (unsigned)__builtin_amdgcn_update_dpp(0, (int)x, 0x118, 0xf, 0xf, true); x = x > t ? x : t; // row_shr:8
    t = (unsigned)__builtin_amdgcn_update_dpp(0, (int)x, 0x142, 0xf, 0xf, true); x = x > t ? x : t; // row_bcast:15
    t = (unsigned)__builtin_amdgcn_update_dpp(0, (int)x, 0x143, 0xf, 0xf, true); x = x > t ? x : t; // row_bcast:31
    return (unsigned)__builtin_amdgcn_readlane((int)x, 63);
}

// Condat's exact 1D TV prox (verified R14 structure; guard counters removed —
// termination is provable: every jump/FF strictly advances k0, every no-jump
// strictly advances k, and the boundary loop strictly advances k0).
__device__ void tv1d_scan(const Dist& v, Dist& o, const int lane)
{
    const float lam = LAM, mlam = -LAM, twolam = TWOLAM;

    // ---- per-scan precompute (vectorized) ----
    Dist vnx;                                    // vnx[j] = v[j+1] for j<255; vnx[255] = v[255]
    {
        float a0 = __shfl_down(v.r0, 1), a1 = __shfl_down(v.r1, 1);
        float a2 = __shfl_down(v.r2, 1), a3 = __shfl_down(v.r3, 1);
        const bool hi = (lane == 63);
        vnx.r0 = hi ? rlane(v.r1, 0) : a0;
        vnx.r1 = hi ? rlane(v.r2, 0) : a1;
        vnx.r2 = hi ? rlane(v.r3, 0) : a2;
        vnx.r3 = hi ? v.r3 : a3;                 // element 255 -> v[255] (safe total fetch)
    }
    Dist d;
    d.r0 = vnx.r0 - v.r0;  d.r1 = vnx.r1 - v.r1;
    d.r2 = vnx.r2 - v.r2;  d.r3 = vnx.r3 - v.r3;
    const unsigned lambits = __float_as_uint(lam);
    Dist sl;                                     // sl[j] = sign(d[j]) * lam
    sl.r0 = __uint_as_float((__float_as_uint(d.r0) & 0x80000000u) | lambits);
    sl.r1 = __uint_as_float((__float_as_uint(d.r1) & 0x80000000u) | lambits);
    sl.r2 = __uint_as_float((__float_as_uint(d.r2) & 0x80000000u) | lambits);
    sl.r3 = __uint_as_float((__float_as_uint(d.r3) & 0x80000000u) | lambits);
    Dist slp;                                    // slp[j] = sl[j-1], slp[0] = 0
    {
        float b0 = __shfl_up(sl.r0, 1), b1 = __shfl_up(sl.r1, 1);
        float b2 = __shfl_up(sl.r2, 1), b3 = __shfl_up(sl.r3, 1);
        const bool lo = (lane == 0);
        slp.r0 = lo ? 0.0f : b0;
        slp.r1 = lo ? rlane(sl.r0, 63) : b1;
        slp.r2 = lo ? rlane(sl.r1, 63) : b2;
        slp.r3 = lo ? rlane(sl.r2, 63) : b3;
    }
    Dist e, g;                                   // e[j] = v[j]+sl[j]-slp[j]; g[j] = v[j]-lam-slp[j]
    {
        float t0 = v.r0 - slp.r0, t1 = v.r1 - slp.r1, t2 = v.r2 - slp.r2, t3 = v.r3 - slp.r3;
        e.r0 = t0 + sl.r0;  e.r1 = t1 + sl.r1;  e.r2 = t2 + sl.r2;  e.r3 = t3 + sl.r3;
        g.r0 = t0 - lam;    g.r1 = t1 - lam;    g.r2 = t2 - lam;    g.r3 = t3 - lam;
    }
    const unsigned long long S0 = __ballot(d.r0 < 0.0f);
    const unsigned long long S1 = __ballot(d.r1 < 0.0f);
    const unsigned long long S2 = __ballot(d.r2 < 0.0f);
    const unsigned long long S3 = __ballot(d.r3 < 0.0f);
    const unsigned long long B20 = __ballot(fabsf(d.r0) > TWOLAM);
    const unsigned long long B21 = __ballot(fabsf(d.r1) > TWOLAM);
    const unsigned long long B22 = __ballot(fabsf(d.r2) > TWOLAM);
    const unsigned long long B23 = __ballot(fabsf(d.r3) > TWOLAM);
    const unsigned long long B40 = __ballot(fabsf(d.r0) > FOURLAM);
    const unsigned long long B41 = __ballot(fabsf(d.r1) > FOURLAM);
    const unsigned long long B42 = __ballot(fabsf(d.r2) > FOURLAM);
    const unsigned long long B43 = __ballot(fabsf(d.r3) > FOURLAM);
    // Sprev shifts S by one element across contiguous words
    const unsigned long long Sp0 = (S0 << 1);
    const unsigned long long Sp1 = (S1 << 1) | (S0 >> 63);
    const unsigned long long Sp2 = (S2 << 1) | (S1 >> 63);
    const unsigned long long Sp3 = (S3 << 1) | (S2 >> 63);
    // run-continuation: F = B4 | (B2 & same-sign-as-prev); NF = ~F (element 255 never forced)
    const unsigned long long NF0 = ~(B40 | (B20 & ~(S0 ^ Sp0)));
    const unsigned long long NF1 = ~(B41 | (B21 & ~(S1 ^ Sp1)));
    const unsigned long long NF2 = ~(B42 | (B22 & ~(S2 ^ Sp2)));
    const unsigned long long NF3 = ~((B43 | (B23 & ~(S3 ^ Sp3))) & 0x7FFFFFFFFFFFFFFFull);
    // post-jump trigger masks by ENTRY direction (threshold: same-dir 2lam, opposite 4lam)
    const unsigned long long FNn0 = (S0 & B20) | (~S0 & B40);
    const unsigned long long FNn1 = (S1 & B21) | (~S1 & B41);
    const unsigned long long FNn2 = (S2 & B22) | (~S2 & B42);
    const unsigned long long FNn3 = (S3 & B23) | (~S3 & B43);
    const unsigned long long FNp0 = (~S0 & B20) | (S0 & B40);
    const unsigned long long FNp1 = (~S1 & B21) | (S1 & B41);
    const unsigned long long FNp2 = (~S2 & B22) | (S2 & B42);
    const unsigned long long FNp3 = (~S3 & B23) | (S3 & B43);
    const int initFF = (int)(B40 & 1ull);        // conservative (|d0|>4lam => forced first jump)

    // first non-forced element >= jmin (fast path: same word)
    auto firstnf = [&](int jmin) -> int {
        const int w = jmin >> 6;
        unsigned long long m = sel4(NF0, NF1, NF2, NF3, w) >> (jmin & 63);
        if (m) return jmin + (int)__builtin_ctzll(m);
        unsigned long long m1 = (w < 1) ? NF1 : 0ull;
        unsigned long long m2 = (w < 2) ? NF2 : 0ull;
        if (m1) return 64 + (int)__builtin_ctzll(m1);
        if (m2) return 128 + (int)__builtin_ctzll(m2);
        return 192 + (int)__builtin_ctzll(NF3);  // NF3 bit63 always set -> reachable & nonzero
    };

    auto trigbit = [&](int kk, int neg) -> int {
        const int w = kk >> 6;
        const unsigned long long m = neg ? sel4(FNn0, FNn1, FNn2, FNn3, w)
                                         : sel4(FNp0, FNp1, FNp2, FNp3, w);
        return (int)((m >> (kk & 63)) & 1ull);
    };

    // ---- serial state ----
    int k = 0, k0 = 0, km = 0, kp = 0;
    float umin = lam, umax = mlam;
    const float v0 = rlane(v.r0, 0);
    float vmin = v0 - lam, vmax = v0 + lam;
    float flen = 1.0f;                  // = k - k0 + 1
    float rnext = 0.5f;                 // invariant: rnext == rcp(flen + 1)
    float vn1 = rlane(vnx.r0, 0);       // v[k+1]

    // pre: standard-fresh at k (=k0=km=kp), next jump forced, k <= N-2.
    // EXIT direction = sign(d[k]) is looked up here (NOT the entry direction).
    auto fastfwd = [&]() {
        const int K1 = firstnf(k + 1);                        // first non-forced j > k (<= 255)
        const int sneg = (int)((sel4(S0, S1, S2, S3, k >> 6) >> (k & 63)) & 1ull); // sign(d[k])
        flushseg(o, k, k, sneg ? vmin : vmax, lane);          // first run element
        if (K1 > k + 1) {                                     // (k, K1-1]: closed-form e[j]
            const int lo = k + 1;
            const unsigned len = (unsigned)(K1 - 1 - lo);
            const int base = lane - lo;
            o.r0 = ((unsigned)(base      ) <= len) ? e.r0 : o.r0;
            o.r1 = ((unsigned)(base + 64 ) <= len) ? e.r1 : o.r1;
            o.r2 = ((unsigned)(base + 128) <= len) ? e.r2 : o.r2;
            o.r3 = ((unsigned)(base + 192) <= len) ? e.r3 : o.r3;
        }
        k = K1; k0 = K1; km = K1; kp = K1;                    // fresh at K1, entry sign = S[K1-1]
        vmin = dfetch(g, K1);                                 // = v[K1] - lam - sl[K1-1]
        vmax = vmin + twolam;
        umin = lam; umax = mlam;
        flen = 1.0f; rnext = 0.5f;
        vn1 = dfetch(vnx, K1);                                // shares lane/sel calc with g fetch
    };

    auto do_step = [&]() {
        // prefetch ALL possible next-position v[k+1] values (off critical path):
        //   no-jump -> k+1; neg-jump landing k0n = km+1 (fresh AND rewind both need
        //   vnx[km+1]); pos-jump landing kp+1. 12 issue-cheap readlanes; the
        //   post-branch dfetch is replaced by a select, cutting the jump->next-un chain.
        const float pf_nj = dfetch(vnx, k + 1);
        const float pf_n  = dfetch(vnx, km + 1);
        const float pf_p  = dfetch(vnx, kp + 1);
        const float un = umin + vn1 - vmin;
        const float ux = umax + vn1 - vmax;
        const bool neg = un < mlam;
        const bool pos = ux > lam;
        // speculative FF-trigger bits for the fresh landing spot k+1 (off-chain SALU)
        const int wn = (k + 1) >> 6, bn = (k + 1) & 63;
        const int tn = (int)((sel4(FNn0, FNn1, FNn2, FNn3, wn) >> bn) & 1ull);
        const int tp = (int)((sel4(FNp0, FNp1, FNp2, FNp3, wn) >> bn) & 1ull);
        if (__builtin_expect((int)(neg | pos), 1)) {          // JUMP
            const float fval = neg ? vmin : vmax;
            const int   fhi  = neg ? km : kp;
            flushseg(o, k0, fhi, fval, lane);
            const int k0n = fhi + 1;
            float vstar;
            int trig;
            if (__builtin_expect((int)(k0n <= k), 0)) {       // rewind (rare)
                vstar = dfetch(v, k0n);
                trig = trigbit(k0n, (int)neg);
            } else {                                          // fresh: renames + precomputed trig
                vstar = vn1;
                trig = neg ? tn : tp;
            }
            k = k0n; k0 = k0n; km = k0n; kp = k0n;
            vmin = neg ? vstar : vstar - twolam;
            vmax = vmin + twolam;
            umin = lam; umax = mlam;
            flen = 1.0f; rnext = 0.5f;
            if (k < N - 1 && trig) {
                fastfwd();                                    // run of guaranteed jumps
            } else {
                vn1 = neg ? pf_n : pf_p;                      // = vnx[k0n] (fresh and rewind)
            }
        } else {                                              // no jump (predicated)
            k++;
            const float r = rnext;                            // = rcp(k - k0 + 1), precomputed
            flen += 1.0f;
            const bool cmin = (un >= lam);
            const bool cmax = (ux <= mlam);
            vmin = cmin ? fmaf(un - lam, r, vmin) : vmin;
            km   = cmin ? k : km;
            umin = cmin ? lam : un;
            vmax = cmax ? fmaf(ux + lam, r, vmax) : vmax;
            kp   = cmax ? k : kp;
            umax = cmax ? mlam : ux;
            vn1 = pf_nj;                                      // = v[k+1] (prefetched)
            rnext = __builtin_amdgcn_rcpf(flen + 1.0f);       // off-chain for next step
        }
    };

    if (initFF) fastfwd();

    for (;;) {
        while (k < N - 1) {
            do_step();
            if (k >= N - 1) break;
            do_step();
        }
        // boundary resolution at k == N-1 (verbatim semantics from verified R2/R6)
        for (;;) {
            if (umin < 0.0f) {
                flushseg(o, k0, km, vmin, lane);
                k0 = km + 1;
                if (k0 > N - 1) return;
                km = k = k0;
                vmin = dfetch(v, k0);
                umin = lam;
                umax = vmin + lam - vmax;
                flen = 1.0f;
            } else if (umax > 0.0f) {
                flushseg(o, k0, kp, vmax, lane);
                k0 = kp + 1;
                if (k0 > N - 1) return;
                kp = k = k0;
                vmax = dfetch(v, k0);
                umax = mlam;
                umin = vmax - lam - vmin;
                flen = 1.0f;
            } else {
                vmin += umin / flen;
                flushseg(o, k0, k, vmin, lane);
                return;
            }
            if (k != N - 1) break;
        }
        rnext = 0.5f;                                         // flen == 1 here
        vn1 = dfetch(vnx, k);                                 // = v[k+1]
    }
}

// Per-WAVE grid barrier over L2-bypassing flag slots (one slot per LINE).
// Arrive: drain only the wave's own data stores, then store {payload,seq}.
// No leading/trailing __syncthreads: the intra-block LDS-tile WAR hazard is
// subsumed by the grid barrier itself (tile reads precede scans which precede
// flag stores), and block-mates are released through a single packed 64-bit
// LDS word {payload,seq} (one location -> relaxed atomics are order-safe).
// Payload-carry invariant preserved: a late bar2 poller may observe a slot
// already advanced to seq+1 (bar1 of it+1), whose payload is that wave's
// accprev == am(it) — the same value. Skew > 1 barrier is impossible.
template <bool WANT>
__device__ __forceinline__ unsigned wavebar(unsigned long long* slots, unsigned seq,
                                            unsigned payload, int line, int lane, int wave,
                                            unsigned long long* s_rel)
{
    __builtin_amdgcn_s_waitcnt(0);                            // own data stores drained
    __hip_atomic_store(&slots[line * SLOTSTRIDE],
                       ((unsigned long long)payload << 32) | (unsigned long long)seq,
                       __ATOMIC_RELAXED, __HIP_MEMORY_SCOPE_AGENT);
    unsigned ga = 0u;
    if (wave == 0) {
        // software-pipelined poll: probe n+1 issues before probe n's ballot resolves
        auto ld = [&](int i) {
            return __hip_atomic_load(&slots[i * SLOTSTRIDE],
                                     __ATOMIC_RELAXED, __HIP_MEMORY_SCOPE_AGENT);
        };
        unsigned long long f0 = ld(lane), f1 = ld(lane + 64),
                           f2 = ld(lane + 128), f3 = ld(lane + 192);
        for (;;) {
            unsigned long long g0 = ld(lane), g1 = ld(lane + 64),
                               g2 = ld(lane + 128), g3 = ld(lane + 192);
            const bool ok = ((unsigned)f0 >= seq) & ((unsigned)f1 >= seq) &
                            ((unsigned)f2 >= seq) & ((unsigned)f3 >= seq);
            if (__all((int)ok)) break;
            f0 = g0; f1 = g1; f2 = g2; f3 = g3;
        }
        if (WANT) {                                           // grid-max of payloads, in-poll
            unsigned a = (unsigned)(f0 >> 32), b = (unsigned)(f1 >> 32);
            unsigned c = (unsigned)(f2 >> 32), d = (unsigned)(f3 >> 32);
            a = a > b ? a : b;  c = c > d ? c : d;  a = a > c ? a : c;
            ga = wredmax(a);                                  // uint order == float order (acc>=0)
        }
        if (lane == 0)
            __hip_atomic_store(s_rel, ((unsigned long long)ga << 32) | (unsigned long long)seq,
                               __ATOMIC_RELAXED, __HIP_MEMORY_SCOPE_WORKGROUP);
    } else {
        unsigned long long r;
        do {
            r = __hip_atomic_load(s_rel, __ATOMIC_RELAXED, __HIP_MEMORY_SCOPE_WORKGROUP);
        } while ((unsigned)r < seq);                          // monotone; packed -> payload atomic w/ seq
        if (WANT) ga = (unsigned)(r >> 32);
    }
    return ga;
}

// Douglas-Rachford TV2D. Wave w of block b owns column (4b+w) in phase 1 and row
// (4b+w) in phase 2. Coalesced 16B sc1 staging loads + LDS transpose; all y/xw
// traffic L2-bypassing so barriers need no cache maintenance.
__global__ __launch_bounds__(NT) void tv2d_coop(const float* __restrict__ X,
                                                float* __restrict__ xw,     // = d_out
                                                float* __restrict__ y,      // holds yT
                                                unsigned long long* __restrict__ slots)
{
    const int t = threadIdx.x;
    const int lane = t & 63;
    const int wave = t >> 6;
    const int line = blockIdx.x * NLINE + wave;
    const int col4 = 4 * blockIdx.x;             // block's 4-column / 4-row group
    __shared__ float tile[N * 5];                // transpose tile, stride-5 padded
    __shared__ unsigned long long s_rel;         // packed {acc, seq} release word
    if (t == 0) s_rel = 0ull;                    // visible via the first tile __syncthreads

    Dist p = {0.f, 0.f, 0.f, 0.f};
    Dist q = {0.f, 0.f, 0.f, 0.f};
    unsigned accprev = 0u;                       // this wave's acc from previous iteration

    for (int it = 0; it < MAXIT; ++it) {
        // ---- column phase: y = prox(x + p) on column `line`; p = v - y ----
        const float* xs = (it == 0) ? X : xw;
        const float4 xc = gload4(xs + t * N + col4);   // 16B L2-bypass load
        tile[t * 5 + 0] = xc.x;                 // transpose deposit: tile[row][c]
        tile[t * 5 + 1] = xc.y;                 // (write-after-read vs previous phase is safe:
        tile[t * 5 + 2] = xc.z;                 //  grid barrier => all waves' reads are done)
        tile[t * 5 + 3] = xc.w;
        __syncthreads();
        Dist v, o;
        v.r0 = tile[(lane      ) * 5 + wave] + p.r0;   // column `line` from LDS
        v.r1 = tile[(lane + 64 ) * 5 + wave] + p.r1;
        v.r2 = tile[(lane + 128) * 5 + wave] + p.r2;
        v.r3 = tile[(lane + 192) * 5 + wave] + p.r3;
        tv1d_scan(v, o, lane);
        p.r0 = v.r0 - o.r0;  p.r1 = v.r1 - o.r1;
        p.r2 = v.r2 - o.r2;  p.r3 = v.r3 - o.r3;
        float* yt = y + line * N;               // y stored TRANSPOSED -> coalesced
        gstore(yt + lane,       o.r0);
        gstore(yt + lane + 64,  o.r1);
        gstore(yt + lane + 128, o.r2);
        gstore(yt + lane + 192, o.r3);
        wavebar<false>(slots, 2u * (unsigned)it + 1u, accprev, line, lane, wave, &s_rel);

        // ---- row phase: x2 = prox(y + q) on row `line`; q = v - x2; acc = max|y-x2| ----
        const float4 yc = gload4(y + t * N + col4);    // 16B L2-bypass load
        tile[t * 5 + 0] = yc.x;                 // tile[j][c] = y[col4+c][j]
        tile[t * 5 + 1] = yc.y;
        tile[t * 5 + 2] = yc.z;
        tile[t * 5 + 3] = yc.w;
        __syncthreads();
        float y0 = tile[(lane      ) * 5 + wave];      // row `line` elements
        float y1 = tile[(lane + 64 ) * 5 + wave];
        float y2 = tile[(lane + 128) * 5 + wave];
        float y3 = tile[(lane + 192) * 5 + wave];
        Dist w, o2;
        w.r0 = y0 + q.r0;
        w.r1 = y1 + q.r1;
        w.r2 = y2 + q.r2;
        w.r3 = y3 + q.r3;
        tv1d_scan(w, o2, lane);
        float d0 = y0 - o2.r0;    // y - x2
        float d1 = y1 - o2.r1;
        float d2 = y2 - o2.r2;
        float d3 = y3 - o2.r3;
        q.r0 = w.r0 - o2.r0;  q.r1 = w.r1 - o2.r1;
        q.r2 = w.r2 - o2.r2;  q.r3 = w.r3 - o2.r3;
        float* xr = xw + line * N;              // row-major, coalesced
        gstore(xr + lane,       o2.r0);
        gstore(xr + lane + 64,  o2.r1);
        gstore(xr + lane + 128, o2.r2);
        gstore(xr + lane + 192, o2.r3);

        float am = fmaxf(fmaxf(fabsf(d0), fabsf(d1)), fmaxf(fabsf(d2), fabsf(d3)));
        const unsigned acc = wredmax(__float_as_uint(am));    // wave max via DPP ladder

        if (it == MAXIT - 1) break;             // nothing after the last row phase is read

        // ---- barrier 2: packed {acc, seq}; grid-max decision computed in-poll ----
        const unsigned ga = wavebar<true>(slots, 2u * (unsigned)it + 2u, acc, line, lane, wave, &s_rel);
        if (__uint_as_float(ga) < TOL) break;   // xw holds x2 of `it` (reference output)
        accprev = acc;
    }
}

extern "C" void kernel_launch(void* const* d_in, const int* in_sizes, int n_in,
                              void* d_out, int out_size, void* d_ws, size_t ws_size,
                              hipStream_t stream) {
    const float* X = (const float*)d_in[0];
    float* xw = (float*)d_out;
    float* y = (float*)d_ws;
    unsigned long long* slots = (unsigned long long*)((char*)d_ws + (size_t)N * N * sizeof(float));
    // zero the slot array (256 slots x 32 B = 8 KB) before the kernel (capture-legal)
    (void)hipMemsetAsync((void*)slots, 0, N * SLOTSTRIDE * sizeof(unsigned long long), stream);
    void* args[] = { (void*)&X, (void*)&xw, (void*)&y, (void*)&slots };
    (void)hipLaunchCooperativeKernel((void*)tv2d_coop, dim3(NB), dim3(NT), args, 0, stream);
}

// Round 2
// 282.265 us; speedup vs baseline: 1.1014x; 1.1014x over previous
//
#include <hip/hip_runtime.h>

#define N 256
#define NLINE 4               // lines (waves) per block
#define NB (N / NLINE)        // 64 blocks
#define NT (NLINE * 64)       // 256 threads
#define LAM 0.05f             // step = ALPHA/2
#define TWOLAM (2.0f * LAM)
#define FOURLAM (4.0f * LAM)
#define MAXIT 35
#define TOL 0.01f
#define SLOTSTRIDE 16         // uint64 elements -> 128 B per block slot (own L3 line)

// broadcast-read one lane's register (lane index is wave-uniform -> v_readlane)
__device__ __forceinline__ float rlane(float v, int lane) {
    return __int_as_float(__builtin_amdgcn_readlane(__float_as_int(v), lane));
}

// agent-scope (L2-bypassing) scalar access for cross-block-communicated arrays.
__device__ __forceinline__ void gstore(float* p, float v) {
    __hip_atomic_store(p, v, __ATOMIC_RELAXED, __HIP_MEMORY_SCOPE_AGENT);
}
// 16-byte L2-bypassing load (sc0 sc1 = coherent scope, L3-served — never caches
// in L2, so the no-cache-maintenance barrier remains correct).
__device__ __forceinline__ float4 gload4(const float* p) {
    float4 r;
    asm volatile("global_load_dwordx4 %0, %1, off sc0 sc1\n\ts_waitcnt vmcnt(0)"
                 : "=&v"(r) : "v"(p) : "memory");
    return r;
}

// 256-float line distributed over the wave: element k lives in lane (k&63), reg (k>>6)
// -> ballot words are CONTIGUOUS 64-element spans (word w = elements 64w..64w+63)
struct Dist { float r0, r1, r2, r3; };

// branchless fetch: 4 independent readlanes + 2 uniform selects
__device__ __forceinline__ float dfetch(const Dist& d, int k) {
    const int lane = k & 63;
    const int sel = k >> 6;
    float a = rlane(d.r0, lane);
    float b = rlane(d.r1, lane);
    float c = rlane(d.r2, lane);
    float e = rlane(d.r3, lane);
    float ab = (sel & 1) ? b : a;
    float ce = (sel & 1) ? e : c;
    return (sel & 2) ? ce : ab;
}

// O(1) segment flush: o[j] = val for j in [lo, hi]; element j of reg r = 64r + lane
__device__ __forceinline__ void flushseg(Dist& o, int lo, int hi, float val, int lane) {
    const unsigned len = (unsigned)(hi - lo);
    const int base = lane - lo;
    o.r0 = ((unsigned)(base      ) <= len) ? val : o.r0;
    o.r1 = ((unsigned)(base + 64 ) <= len) ? val : o.r1;
    o.r2 = ((unsigned)(base + 128) <= len) ? val : o.r2;
    o.r3 = ((unsigned)(base + 192) <= len) ? val : o.r3;
}

// scalar 4-way select of a 64-bit mask (s_cselect_b64)
__device__ __forceinline__ unsigned long long sel4(unsigned long long a, unsigned long long b,
                                                   unsigned long long c, unsigned long long d, int r) {
    unsigned long long ab = (r & 1) ? b : a;
    unsigned long long cd = (r & 1) ? d : c;
    return (r & 2) ? cd : ab;
}

// full-wave (64-lane) max of a nonneg-float-as-uint via the canonical gfx9 DPP
// ladder (row_shr 1,2,4,8 + row_bcast 15,31 -> lane 63 holds the total, then
// readlane broadcast). ~6 back-to-back VALU ops (~50 cy) vs 6 serial
// ds_bpermute round-trips (~250 cy) for a __shfl_xor ladder. Verified correct
// in the R1 run (bitwise-identical convergence decisions).
__device__ __forceinline__ unsigned wredmax(unsigned x) {
    unsigned t;
    t = (unsigned)__builtin_amdgcn_update_dpp(0, (int)x, 0x111, 0xf, 0xf, true); x = x > t ? x : t; // row_shr:1
    t = (unsigned)__builtin_amdgcn_update_dpp(0, (int)x, 0x112, 0xf, 0xf, true); x = x > t ? x : t; // row_shr:2
    t = (unsigned)__builtin_amdgcn_update_dpp(0, (int)x, 0x114, 0xf, 0xf, true); x = x > t ? x : t; // row_shr:4
    t = (unsigned)__builtin_amdgcn_update_dpp(0, (int)x, 0x118, 0xf, 0xf, true); x = x > t ? x : t; // row_shr:8
    t = (unsigned)__builtin_amdgcn_update_dpp(0, (int)x, 0x142, 0xf, 0xf, true); x = x > t ? x : t; // row_bcast:15
    t = (unsigned)__builtin_amdgcn_update_dpp(0, (int)x, 0x143, 0xf, 0xf, true); x = x > t ? x : t; // row_bcast:31
    return (unsigned)__builtin_amdgcn_readlane((int)x, 63);
}

// Condat's exact 1D TV prox (verified R14 structure; guard counters removed —
// termination is provable: every jump/FF strictly advances k0, every no-jump
// strictly advances k, and the boundary loop strictly advances k0).
// NOTE (R1 lesson): with ~1 wave/SIMD, program order == critical path. Do NOT
// add speculative work ahead of the un/ux -> compare -> branch chain.
__device__ void tv1d_scan(const Dist& v, Dist& o, const int lane)
{
    const float lam = LAM, mlam = -LAM, twolam = TWOLAM;

    // ---- per-scan precompute (vectorized) ----
    Dist vnx;                                    // vnx[j] = v[j+1] for j<255; vnx[255] = v[255]
    {
        float a0 = __shfl_down(v.r0, 1), a1 = __shfl_down(v.r1, 1);
        float a2 = __shfl_down(v.r2, 1), a3 = __shfl_down(v.r3, 1);
        const bool hi = (lane == 63);
        vnx.r0 = hi ? rlane(v.r1, 0) : a0;
        vnx.r1 = hi ? rlane(v.r2, 0) : a1;
        vnx.r2 = hi ? rlane(v.r3, 0) : a2;
        vnx.r3 = hi ? v.r3 : a3;                 // element 255 -> v[255] (safe total fetch)
    }
    Dist d;
    d.r0 = vnx.r0 - v.r0;  d.r1 = vnx.r1 - v.r1;
    d.r2 = vnx.r2 - v.r2;  d.r3 = vnx.r3 - v.r3;
    const unsigned lambits = __float_as_uint(lam);
    Dist sl;                                     // sl[j] = sign(d[j]) * lam
    sl.r0 = __uint_as_float((__float_as_uint(d.r0) & 0x80000000u) | lambits);
    sl.r1 = __uint_as_float((__float_as_uint(d.r1) & 0x80000000u) | lambits);
    sl.r2 = __uint_as_float((__float_as_uint(d.r2) & 0x80000000u) | lambits);
    sl.r3 = __uint_as_float((__float_as_uint(d.r3) & 0x80000000u) | lambits);
    Dist slp;                                    // slp[j] = sl[j-1], slp[0] = 0
    {
        float b0 = __shfl_up(sl.r0, 1), b1 = __shfl_up(sl.r1, 1);
        float b2 = __shfl_up(sl.r2, 1), b3 = __shfl_up(sl.r3, 1);
        const bool lo = (lane == 0);
        slp.r0 = lo ? 0.0f : b0;
        slp.r1 = lo ? rlane(sl.r0, 63) : b1;
        slp.r2 = lo ? rlane(sl.r1, 63) : b2;
        slp.r3 = lo ? rlane(sl.r2, 63) : b3;
    }
    Dist e, g;                                   // e[j] = v[j]+sl[j]-slp[j]; g[j] = v[j]-lam-slp[j]
    {
        float t0 = v.r0 - slp.r0, t1 = v.r1 - slp.r1, t2 = v.r2 - slp.r2, t3 = v.r3 - slp.r3;
        e.r0 = t0 + sl.r0;  e.r1 = t1 + sl.r1;  e.r2 = t2 + sl.r2;  e.r3 = t3 + sl.r3;
        g.r0 = t0 - lam;    g.r1 = t1 - lam;    g.r2 = t2 - lam;    g.r3 = t3 - lam;
    }
    const unsigned long long S0 = __ballot(d.r0 < 0.0f);
    const unsigned long long S1 = __ballot(d.r1 < 0.0f);
    const unsigned long long S2 = __ballot(d.r2 < 0.0f);
    const unsigned long long S3 = __ballot(d.r3 < 0.0f);
    const unsigned long long B20 = __ballot(fabsf(d.r0) > TWOLAM);
    const unsigned long long B21 = __ballot(fabsf(d.r1) > TWOLAM);
    const unsigned long long B22 = __ballot(fabsf(d.r2) > TWOLAM);
    const unsigned long long B23 = __ballot(fabsf(d.r3) > TWOLAM);
    const unsigned long long B40 = __ballot(fabsf(d.r0) > FOURLAM);
    const unsigned long long B41 = __ballot(fabsf(d.r1) > FOURLAM);
    const unsigned long long B42 = __ballot(fabsf(d.r2) > FOURLAM);
    const unsigned long long B43 = __ballot(fabsf(d.r3) > FOURLAM);
    // Sprev shifts S by one element across contiguous words
    const unsigned long long Sp0 = (S0 << 1);
    const unsigned long long Sp1 = (S1 << 1) | (S0 >> 63);
    const unsigned long long Sp2 = (S2 << 1) | (S1 >> 63);
    const unsigned long long Sp3 = (S3 << 1) | (S2 >> 63);
    // run-continuation: F = B4 | (B2 & same-sign-as-prev); NF = ~F (element 255 never forced)
    const unsigned long long NF0 = ~(B40 | (B20 & ~(S0 ^ Sp0)));
    const unsigned long long NF1 = ~(B41 | (B21 & ~(S1 ^ Sp1)));
    const unsigned long long NF2 = ~(B42 | (B22 & ~(S2 ^ Sp2)));
    const unsigned long long NF3 = ~((B43 | (B23 & ~(S3 ^ Sp3))) & 0x7FFFFFFFFFFFFFFFull);
    // post-jump trigger masks by ENTRY direction (threshold: same-dir 2lam, opposite 4lam)
    const unsigned long long FNn0 = (S0 & B20) | (~S0 & B40);
    const unsigned long long FNn1 = (S1 & B21) | (~S1 & B41);
    const unsigned long long FNn2 = (S2 & B22) | (~S2 & B42);
    const unsigned long long FNn3 = (S3 & B23) | (~S3 & B43);
    const unsigned long long FNp0 = (~S0 & B20) | (S0 & B40);
    const unsigned long long FNp1 = (~S1 & B21) | (S1 & B41);
    const unsigned long long FNp2 = (~S2 & B22) | (S2 & B42);
    const unsigned long long FNp3 = (~S3 & B23) | (S3 & B43);
    const int initFF = (int)(B40 & 1ull);        // conservative (|d0|>4lam => forced first jump)

    // first non-forced element >= jmin (fast path: same word)
    auto firstnf = [&](int jmin) -> int {
        const int w = jmin >> 6;
        unsigned long long m = sel4(NF0, NF1, NF2, NF3, w) >> (jmin & 63);
        if (m) return jmin + (int)__builtin_ctzll(m);
        unsigned long long m1 = (w < 1) ? NF1 : 0ull;
        unsigned long long m2 = (w < 2) ? NF2 : 0ull;
        if (m1) return 64 + (int)__builtin_ctzll(m1);
        if (m2) return 128 + (int)__builtin_ctzll(m2);
        return 192 + (int)__builtin_ctzll(NF3);  // NF3 bit63 always set -> reachable & nonzero
    };

    auto trigbit = [&](int kk, int neg) -> int {
        const int w = kk >> 6;
        const unsigned long long m = neg ? sel4(FNn0, FNn1, FNn2, FNn3, w)
                                         : sel4(FNp0, FNp1, FNp2, FNp3, w);
        return (int)((m >> (kk & 63)) & 1ull);
    };

    // ---- serial state ----
    int k = 0, k0 = 0, km = 0, kp = 0;
    float umin = lam, umax = mlam;
    const float v0 = rlane(v.r0, 0);
    float vmin = v0 - lam, vmax = v0 + lam;
    float flen = 1.0f;                  // = k - k0 + 1
    float rnext = 0.5f;                 // invariant: rnext == rcp(flen + 1)
    float vn1 = rlane(vnx.r0, 0);       // v[k+1]

    // pre: standard-fresh at k (=k0=km=kp), next jump forced, k <= N-2.
    // EXIT direction = sign(d[k]) is looked up here (NOT the entry direction).
    auto fastfwd = [&]() {
        const int K1 = firstnf(k + 1);                        // first non-forced j > k (<= 255)
        const int sneg = (int)((sel4(S0, S1, S2, S3, k >> 6) >> (k & 63)) & 1ull); // sign(d[k])
        flushseg(o, k, k, sneg ? vmin : vmax, lane);          // first run element
        if (K1 > k + 1) {                                     // (k, K1-1]: closed-form e[j]
            const int lo = k + 1;
            const unsigned len = (unsigned)(K1 - 1 - lo);
            const int base = lane - lo;
            o.r0 = ((unsigned)(base      ) <= len) ? e.r0 : o.r0;
            o.r1 = ((unsigned)(base + 64 ) <= len) ? e.r1 : o.r1;
            o.r2 = ((unsigned)(base + 128) <= len) ? e.r2 : o.r2;
            o.r3 = ((unsigned)(base + 192) <= len) ? e.r3 : o.r3;
        }
        k = K1; k0 = K1; km = K1; kp = K1;                    // fresh at K1, entry sign = S[K1-1]
        vmin = dfetch(g, K1);                                 // = v[K1] - lam - sl[K1-1]
        vmax = vmin + twolam;
        umin = lam; umax = mlam;
        flen = 1.0f; rnext = 0.5f;
        vn1 = dfetch(vnx, K1);                                // shares lane/sel calc with g fetch
    };

    auto do_step = [&]() {
        const float un = umin + vn1 - vmin;
        const float ux = umax + vn1 - vmax;
        const bool neg = un < mlam;
        const bool pos = ux > lam;
        // speculative FF-trigger bits for the fresh landing spot k+1 (off-chain SALU)
        const int wn = (k + 1) >> 6, bn = (k + 1) & 63;
        const int tn = (int)((sel4(FNn0, FNn1, FNn2, FNn3, wn) >> bn) & 1ull);
        const int tp = (int)((sel4(FNp0, FNp1, FNp2, FNp3, wn) >> bn) & 1ull);
        if (__builtin_expect((int)(neg | pos), 1)) {          // JUMP
            const float fval = neg ? vmin : vmax;
            const int   fhi  = neg ? km : kp;
            flushseg(o, k0, fhi, fval, lane);
            const int k0n = fhi + 1;
            float vstar;
            int trig;
            if (__builtin_expect((int)(k0n <= k), 0)) {       // rewind (rare)
                vstar = dfetch(v, k0n);
                trig = trigbit(k0n, (int)neg);
            } else {                                          // fresh: renames + precomputed trig
                vstar = vn1;
                trig = neg ? tn : tp;
            }
            k = k0n; k0 = k0n; km = k0n; kp = k0n;
            vmin = neg ? vstar : vstar - twolam;
            vmax = vmin + twolam;
            umin = lam; umax = mlam;
            flen = 1.0f; rnext = 0.5f;
            if (k < N - 1 && trig) {
                fastfwd();                                    // run of guaranteed jumps
            } else {
                vn1 = dfetch(vnx, k);                         // = v[k+1] (total, clamp-free)
            }
        } else {                                              // no jump (predicated)
            k++;
            const float r = rnext;                            // = rcp(k - k0 + 1), precomputed
            flen += 1.0f;
            const bool cmin = (un >= lam);
            const bool cmax = (ux <= mlam);
            vmin = cmin ? fmaf(un - lam, r, vmin) : vmin;
            km   = cmin ? k : km;
            umin = cmin ? lam : un;
            vmax = cmax ? fmaf(ux + lam, r, vmax) : vmax;
            kp   = cmax ? k : kp;
            umax = cmax ? mlam : ux;
            vn1 = dfetch(vnx, k);                             // = v[k+1] (total, clamp-free)
            rnext = __builtin_amdgcn_rcpf(flen + 1.0f);       // off-chain for next step
        }
    };

    if (initFF) fastfwd();

    for (;;) {
        while (k < N - 1) {
            do_step();
            if (k >= N - 1) break;
            do_step();
        }
        // boundary resolution at k == N-1 (verbatim semantics from verified R2/R6)
        for (;;) {
            if (umin < 0.0f) {
                flushseg(o, k0, km, vmin, lane);
                k0 = km + 1;
                if (k0 > N - 1) return;
                km = k = k0;
                vmin = dfetch(v, k0);
                umin = lam;
                umax = vmin + lam - vmax;
                flen = 1.0f;
            } else if (umax > 0.0f) {
                flushseg(o, k0, kp, vmax, lane);
                k0 = kp + 1;
                if (k0 > N - 1) return;
                kp = k = k0;
                vmax = dfetch(v, k0);
                umax = mlam;
                umin = vmax - lam - vmin;
                flen = 1.0f;
            } else {
                vmin += umin / flen;
                flushseg(o, k0, k, vmin, lane);
                return;
            }
            if (k != N - 1) break;
        }
        rnext = 0.5f;                                         // flen == 1 here
        vn1 = dfetch(vnx, k);                                 // = v[k+1]
    }
}

// Packed-slot grid barrier over L2-bypassing data: NO cache wb/inv, ordering only.
// Poll is software-pipelined: probe n+1 issues before probe n's ballot resolves.
__device__ __forceinline__ void gridbar1(unsigned long long* slots, unsigned seq,
                                         unsigned accfill, int t) {
    __syncthreads();
    __builtin_amdgcn_s_waitcnt(0);                            // y-stores drained before flag store
    if (t == 0)
        __hip_atomic_store(&slots[blockIdx.x * SLOTSTRIDE],
                           ((unsigned long long)accfill << 32) | (unsigned long long)seq,
                           __ATOMIC_RELAXED, __HIP_MEMORY_SCOPE_AGENT);
    if (t < 64) {
        unsigned long long f = __hip_atomic_load(&slots[t * SLOTSTRIDE],
                                                 __ATOMIC_RELAXED, __HIP_MEMORY_SCOPE_AGENT);
        for (;;) {
            unsigned long long fn = __hip_atomic_load(&slots[t * SLOTSTRIDE],
                                                      __ATOMIC_RELAXED, __HIP_MEMORY_SCOPE_AGENT);
            if (__all((int)((unsigned)f >= seq))) break;      // check overlaps next probe
            f = fn;
        }
    }
    __syncthreads();
}

// barrier 2: payload-carrying; computes the grid-wide convergence decision from
// the poll's final values (free — no separate round trip). DPP ladder replaces
// the 6-deep serial ds_bpermute shuffle ladder (~-200 cy on the release path).
__device__ __forceinline__ void gridbar2(unsigned long long* slots, unsigned seq,
                                         unsigned acc, int t, int* s_dec) {
    __syncthreads();
    __builtin_amdgcn_s_waitcnt(0);                            // x2-stores drained before flag store
    if (t == 0)
        __hip_atomic_store(&slots[blockIdx.x * SLOTSTRIDE],
                           ((unsigned long long)acc << 32) | (unsigned long long)seq,
                           __ATOMIC_RELAXED, __HIP_MEMORY_SCOPE_AGENT);
    if (t < 64) {
        unsigned long long f = __hip_atomic_load(&slots[t * SLOTSTRIDE],
                                                 __ATOMIC_RELAXED, __HIP_MEMORY_SCOPE_AGENT);
        for (;;) {
            unsigned long long fn = __hip_atomic_load(&slots[t * SLOTSTRIDE],
                                                      __ATOMIC_RELAXED, __HIP_MEMORY_SCOPE_AGENT);
            if (__all((int)((unsigned)f >= seq))) break;
            f = fn;
        }
        unsigned a = wredmax((unsigned)(f >> 32));            // uint order == float order (acc>=0)
        if (t == 0) *s_dec = (__uint_as_float(a) < TOL) ? 1 : 0;
    }
    __syncthreads();
}

// Douglas-Rachford TV2D. Wave w of block b owns column (4b+w) in phase 1 and row
// (4b+w) in phase 2. Coalesced 16B sc1 staging loads + LDS transpose; all y/xw
// traffic L2-bypassing so barriers need no cache maintenance.
__global__ __launch_bounds__(NT) void tv2d_coop(const float* __restrict__ X,
                                                float* __restrict__ xw,     // = d_out
                                                float* __restrict__ y,      // holds yT
                                                unsigned long long* __restrict__ slots)
{
    const int t = threadIdx.x;
    const int lane = t & 63;
    const int wave = t >> 6;
    const int line = blockIdx.x * NLINE + wave;
    const int col4 = 4 * blockIdx.x;             // block's 4-column / 4-row group
    __shared__ float tile[N * 5];                // transpose tile, stride-5 padded
    __shared__ unsigned s_acc;
    __shared__ int s_dec;
    if (t == 0) s_acc = 0u;

    Dist p = {0.f, 0.f, 0.f, 0.f};
    Dist q = {0.f, 0.f, 0.f, 0.f};
    unsigned accprev = 0u;                       // block's acc from previous iteration

    for (int it = 0; it < MAXIT; ++it) {
        // ---- column phase: y = prox(x + p) on column `line`; p = v - y ----
        const float* xs = (it == 0) ? X : xw;
        const float4 xc = gload4(xs + t * N + col4);   // 16B L2-bypass load
        tile[t * 5 + 0] = xc.x;                 // transpose deposit: tile[row][c]
        tile[t * 5 + 1] = xc.y;
        tile[t * 5 + 2] = xc.z;
        tile[t * 5 + 3] = xc.w;
        __syncthreads();
        Dist v, o;
        v.r0 = tile[(lane      ) * 5 + wave] + p.r0;   // column `line` from LDS
        v.r1 = tile[(lane + 64 ) * 5 + wave] + p.r1;
        v.r2 = tile[(lane + 128) * 5 + wave] + p.r2;
        v.r3 = tile[(lane + 192) * 5 + wave] + p.r3;
        tv1d_scan(v, o, lane);
        p.r0 = v.r0 - o.r0;  p.r1 = v.r1 - o.r1;
        p.r2 = v.r2 - o.r2;  p.r3 = v.r3 - o.r3;
        float* yt = y + line * N;               // y stored TRANSPOSED -> coalesced
        gstore(yt + lane,       o.r0);
        gstore(yt + lane + 64,  o.r1);
        gstore(yt + lane + 128, o.r2);
        gstore(yt + lane + 192, o.r3);
        gridbar1(slots, 2u * (unsigned)it + 1u, accprev, t);

        // ---- row phase: x2 = prox(y + q) on row `line`; q = v - x2; acc = max|y-x2| ----
        const float4 yc = gload4(y + t * N + col4);    // 16B L2-bypass load
        tile[t * 5 + 0] = yc.x;                 // tile[j][c] = y[col4+c][j]
        tile[t * 5 + 1] = yc.y;
        tile[t * 5 + 2] = yc.z;
        tile[t * 5 + 3] = yc.w;
        __syncthreads();
        float y0 = tile[(lane      ) * 5 + wave];      // row `line` elements
        float y1 = tile[(lane + 64 ) * 5 + wave];
        float y2 = tile[(lane + 128) * 5 + wave];
        float y3 = tile[(lane + 192) * 5 + wave];
        Dist w, o2;
        w.r0 = y0 + q.r0;
        w.r1 = y1 + q.r1;
        w.r2 = y2 + q.r2;
        w.r3 = y3 + q.r3;
        tv1d_scan(w, o2, lane);
        float d0 = y0 - o2.r0;    // y - x2
        float d1 = y1 - o2.r1;
        float d2 = y2 - o2.r2;
        float d3 = y3 - o2.r3;
        q.r0 = w.r0 - o2.r0;  q.r1 = w.r1 - o2.r1;
        q.r2 = w.r2 - o2.r2;  q.r3 = w.r3 - o2.r3;
        float* xr = xw + line * N;              // row-major, coalesced
        gstore(xr + lane,       o2.r0);
        gstore(xr + lane + 64,  o2.r1);
        gstore(xr + lane + 128, o2.r2);
        gstore(xr + lane + 192, o2.r3);

        float am = fmaxf(fmaxf(fabsf(d0), fabsf(d1)), fmaxf(fabsf(d2), fabsf(d3)));
        const unsigned amu = wredmax(__float_as_uint(am));       // DPP ladder (was shfl_xor x6)
        if (lane == 0) atomicMax(&s_acc, amu);                   // LDS atomic, 4/block
        __syncthreads();                                          // s_acc complete
        const unsigned ba = s_acc;                                // everyone reads before reset

        if (it == MAXIT - 1) break;             // nothing after the last row phase is read

        // ---- barrier 2: packed {acc, seq}; decision computed in-poll ----
        gridbar2(slots, 2u * (unsigned)it + 2u, ba, t, &s_dec);   // leading syncthreads orders ba reads
        if (t == 0) s_acc = 0u;                 // safe: next atomicMax is after gridbar1 of it+1
        if (s_dec) break;                       // xw holds x2 of `it` (reference output)
        accprev = ba;
    }
}

extern "C" void kernel_launch(void* const* d_in, const int* in_sizes, int n_in,
                              void* d_out, int out_size, void* d_ws, size_t ws_size,
                              hipStream_t stream) {
    const float* X = (const float*)d_in[0];
    float* xw = (float*)d_out;
    float* y = (float*)d_ws;
    unsigned long long* slots = (unsigned long long*)((char*)d_ws + (size_t)N * N * sizeof(float));
    // zero the slot array (64 slots x 128 B) before the kernel (capture-legal)
    (void)hipMemsetAsync((void*)slots, 0, NB * SLOTSTRIDE * sizeof(unsigned long long), stream);
    void* args[] = { (void*)&X, (void*)&xw, (void*)&y, (void*)&slots };
    (void)hipLaunchCooperativeKernel((void*)tv2d_coop, dim3(NB), dim3(NT), args, 0, stream);
}

// Round 3
// 271.123 us; speedup vs baseline: 1.1466x; 1.0411x over previous
//
#include <hip/hip_runtime.h>

#define N 256
#define NB 256                // one block per LINE (one wave per block, one block per CU)
#define NT 64                 // single wave
#define LAM 0.05f             // step = ALPHA/2
#define TWOLAM (2.0f * LAM)
#define FOURLAM (4.0f * LAM)
#define MAXIT 35
#define TOL 0.01f
#define SLOTSTRIDE 2          // uint64 elements -> 16 B per line slot; 256 slots = 4 KB

// broadcast-read one lane's register (lane index is wave-uniform -> v_readlane)
__device__ __forceinline__ float rlane(float v, int lane) {
    return __int_as_float(__builtin_amdgcn_readlane(__float_as_int(v), lane));
}

// agent-scope (L2-bypassing) scalar access for cross-wave-communicated arrays.
__device__ __forceinline__ void gstore(float* p, float v) {
    __hip_atomic_store(p, v, __ATOMIC_RELAXED, __HIP_MEMORY_SCOPE_AGENT);
}

// Scattered COLUMN read of a row-major matrix: element j = 64r+lane of column c
// lives at mat[(64r+lane)*N + c]. 4 stride-1KB loads (64 distinct lines each),
// ONE vmcnt wait -> a single L3 round trip. sc0 sc1 = L2-bypassing/coherent, so
// flag-then-data ordering through L3 holds with no cache maintenance. The
// volatile asm + memory clobber also fences the compiler: these loads cannot be
// hoisted above the preceding barrier poll.
__device__ __forceinline__ void gload_col(const float* mat, int c, int lane, float& a,
                                          float& b, float& d, float& e) {
    const float* p0 = mat + (size_t)lane * N + c;
    const float* p1 = p0 + 64 * N;
    const float* p2 = p0 + 128 * N;
    const float* p3 = p0 + 192 * N;
    asm volatile("global_load_dword %0, %4, off sc0 sc1\n\t"
                 "global_load_dword %1, %5, off sc0 sc1\n\t"
                 "global_load_dword %2, %6, off sc0 sc1\n\t"
                 "global_load_dword %3, %7, off sc0 sc1\n\t"
                 "s_waitcnt vmcnt(0)"
                 : "=&v"(a), "=&v"(b), "=&v"(d), "=&v"(e)
                 : "v"(p0), "v"(p1), "v"(p2), "v"(p3)
                 : "memory");
}

// 256-float line distributed over the wave: element k lives in lane (k&63), reg (k>>6)
// -> ballot words are CONTIGUOUS 64-element spans (word w = elements 64w..64w+63)
struct Dist { float r0, r1, r2, r3; };

// branchless fetch: 4 independent readlanes + 2 uniform selects
__device__ __forceinline__ float dfetch(const Dist& d, int k) {
    const int lane = k & 63;
    const int sel = k >> 6;
    float a = rlane(d.r0, lane);
    float b = rlane(d.r1, lane);
    float c = rlane(d.r2, lane);
    float e = rlane(d.r3, lane);
    float ab = (sel & 1) ? b : a;
    float ce = (sel & 1) ? e : c;
    return (sel & 2) ? ce : ab;
}

// O(1) segment flush: o[j] = val for j in [lo, hi]; element j of reg r = 64r + lane
__device__ __forceinline__ void flushseg(Dist& o, int lo, int hi, float val, int lane) {
    const unsigned len = (unsigned)(hi - lo);
    const int base = lane - lo;
    o.r0 = ((unsigned)(base      ) <= len) ? val : o.r0;
    o.r1 = ((unsigned)(base + 64 ) <= len) ? val : o.r1;
    o.r2 = ((unsigned)(base + 128) <= len) ? val : o.r2;
    o.r3 = ((unsigned)(base + 192) <= len) ? val : o.r3;
}

// scalar 4-way select of a 64-bit mask (s_cselect_b64)
__device__ __forceinline__ unsigned long long sel4(unsigned long long a, unsigned long long b,
                                                   unsigned long long c, unsigned long long d, int r) {
    unsigned long long ab = (r & 1) ? b : a;
    unsigned long long cd = (r & 1) ? d : c;
    return (r & 2) ? cd : ab;
}

// full-wave (64-lane) max of a nonneg-float-as-uint via the canonical gfx9 DPP
// ladder (row_shr 1,2,4,8 + row_bcast 15,31 -> lane 63 holds the total, then
// readlane broadcast). Verified bitwise-correct in R1/R2 runs.
__device__ __forceinline__ unsigned wredmax(unsigned x) {
    unsigned t;
    t = (unsigned)__builtin_amdgcn_update_dpp(0, (int)x, 0x111, 0xf, 0xf, true); x = x > t ? x : t; // row_shr:1
    t = (unsigned)__builtin_amdgcn_update_dpp(0, (int)x, 0x112, 0xf, 0xf, true); x = x > t ? x : t; // row_shr:2
    t = (unsigned)__builtin_amdgcn_update_dpp(0, (int)x, 0x114, 0xf, 0xf, true); x = x > t ? x : t; // row_shr:4
    t = (unsigned)__builtin_amdgcn_update_dpp(0, (int)x, 0x118, 0xf, 0xf, true); x = x > t ? x : t; // row_shr:8
    t = (unsigned)__builtin_amdgcn_update_dpp(0, (int)x, 0x142, 0xf, 0xf, true); x = x > t ? x : t; // row_bcast:15
    t = (unsigned)__builtin_amdgcn_update_dpp(0, (int)x, 0x143, 0xf, 0xf, true); x = x > t ? x : t; // row_bcast:31
    return (unsigned)__builtin_amdgcn_readlane((int)x, 63);
}

// Condat's exact 1D TV prox (verified structure — UNCHANGED from the 213 µs R0/R2
// kernel). NOTE (R1 lesson): with 1 wave/SIMD, program order == critical path.
// Do NOT add speculative work ahead of the un/ux -> compare -> branch chain.
__device__ void tv1d_scan(const Dist& v, Dist& o, const int lane)
{
    const float lam = LAM, mlam = -LAM, twolam = TWOLAM;

    // ---- per-scan precompute (vectorized) ----
    Dist vnx;                                    // vnx[j] = v[j+1] for j<255; vnx[255] = v[255]
    {
        float a0 = __shfl_down(v.r0, 1), a1 = __shfl_down(v.r1, 1);
        float a2 = __shfl_down(v.r2, 1), a3 = __shfl_down(v.r3, 1);
        const bool hi = (lane == 63);
        vnx.r0 = hi ? rlane(v.r1, 0) : a0;
        vnx.r1 = hi ? rlane(v.r2, 0) : a1;
        vnx.r2 = hi ? rlane(v.r3, 0) : a2;
        vnx.r3 = hi ? v.r3 : a3;                 // element 255 -> v[255] (safe total fetch)
    }
    Dist d;
    d.r0 = vnx.r0 - v.r0;  d.r1 = vnx.r1 - v.r1;
    d.r2 = vnx.r2 - v.r2;  d.r3 = vnx.r3 - v.r3;
    const unsigned lambits = __float_as_uint(lam);
    Dist sl;                                     // sl[j] = sign(d[j]) * lam
    sl.r0 = __uint_as_float((__float_as_uint(d.r0) & 0x80000000u) | lambits);
    sl.r1 = __uint_as_float((__float_as_uint(d.r1) & 0x80000000u) | lambits);
    sl.r2 = __uint_as_float((__float_as_uint(d.r2) & 0x80000000u) | lambits);
    sl.r3 = __uint_as_float((__float_as_uint(d.r3) & 0x80000000u) | lambits);
    Dist slp;                                    // slp[j] = sl[j-1], slp[0] = 0
    {
        float b0 = __shfl_up(sl.r0, 1), b1 = __shfl_up(sl.r1, 1);
        float b2 = __shfl_up(sl.r2, 1), b3 = __shfl_up(sl.r3, 1);
        const bool lo = (lane == 0);
        slp.r0 = lo ? 0.0f : b0;
        slp.r1 = lo ? rlane(sl.r0, 63) : b1;
        slp.r2 = lo ? rlane(sl.r1, 63) : b2;
        slp.r3 = lo ? rlane(sl.r2, 63) : b3;
    }
    Dist e, g;                                   // e[j] = v[j]+sl[j]-slp[j]; g[j] = v[j]-lam-slp[j]
    {
        float t0 = v.r0 - slp.r0, t1 = v.r1 - slp.r1, t2 = v.r2 - slp.r2, t3 = v.r3 - slp.r3;
        e.r0 = t0 + sl.r0;  e.r1 = t1 + sl.r1;  e.r2 = t2 + sl.r2;  e.r3 = t3 + sl.r3;
        g.r0 = t0 - lam;    g.r1 = t1 - lam;    g.r2 = t2 - lam;    g.r3 = t3 - lam;
    }
    const unsigned long long S0 = __ballot(d.r0 < 0.0f);
    const unsigned long long S1 = __ballot(d.r1 < 0.0f);
    const unsigned long long S2 = __ballot(d.r2 < 0.0f);
    const unsigned long long S3 = __ballot(d.r3 < 0.0f);
    const unsigned long long B20 = __ballot(fabsf(d.r0) > TWOLAM);
    const unsigned long long B21 = __ballot(fabsf(d.r1) > TWOLAM);
    const unsigned long long B22 = __ballot(fabsf(d.r2) > TWOLAM);
    const unsigned long long B23 = __ballot(fabsf(d.r3) > TWOLAM);
    const unsigned long long B40 = __ballot(fabsf(d.r0) > FOURLAM);
    const unsigned long long B41 = __ballot(fabsf(d.r1) > FOURLAM);
    const unsigned long long B42 = __ballot(fabsf(d.r2) > FOURLAM);
    const unsigned long long B43 = __ballot(fabsf(d.r3) > FOURLAM);
    // Sprev shifts S by one element across contiguous words
    const unsigned long long Sp0 = (S0 << 1);
    const unsigned long long Sp1 = (S1 << 1) | (S0 >> 63);
    const unsigned long long Sp2 = (S2 << 1) | (S1 >> 63);
    const unsigned long long Sp3 = (S3 << 1) | (S2 >> 63);
    // run-continuation: F = B4 | (B2 & same-sign-as-prev); NF = ~F (element 255 never forced)
    const unsigned long long NF0 = ~(B40 | (B20 & ~(S0 ^ Sp0)));
    const unsigned long long NF1 = ~(B41 | (B21 & ~(S1 ^ Sp1)));
    const unsigned long long NF2 = ~(B42 | (B22 & ~(S2 ^ Sp2)));
    const unsigned long long NF3 = ~((B43 | (B23 & ~(S3 ^ Sp3))) & 0x7FFFFFFFFFFFFFFFull);
    // post-jump trigger masks by ENTRY direction (threshold: same-dir 2lam, opposite 4lam)
    const unsigned long long FNn0 = (S0 & B20) | (~S0 & B40);
    const unsigned long long FNn1 = (S1 & B21) | (~S1 & B41);
    const unsigned long long FNn2 = (S2 & B22) | (~S2 & B42);
    const unsigned long long FNn3 = (S3 & B23) | (~S3 & B43);
    const unsigned long long FNp0 = (~S0 & B20) | (S0 & B40);
    const unsigned long long FNp1 = (~S1 & B21) | (S1 & B41);
    const unsigned long long FNp2 = (~S2 & B22) | (S2 & B42);
    const unsigned long long FNp3 = (~S3 & B23) | (S3 & B43);
    const int initFF = (int)(B40 & 1ull);        // conservative (|d0|>4lam => forced first jump)

    // first non-forced element >= jmin (fast path: same word)
    auto firstnf = [&](int jmin) -> int {
        const int w = jmin >> 6;
        unsigned long long m = sel4(NF0, NF1, NF2, NF3, w) >> (jmin & 63);
        if (m) return jmin + (int)__builtin_ctzll(m);
        unsigned long long m1 = (w < 1) ? NF1 : 0ull;
        unsigned long long m2 = (w < 2) ? NF2 : 0ull;
        if (m1) return 64 + (int)__builtin_ctzll(m1);
        if (m2) return 128 + (int)__builtin_ctzll(m2);
        return 192 + (int)__builtin_ctzll(NF3);  // NF3 bit63 always set -> reachable & nonzero
    };

    auto trigbit = [&](int kk, int neg) -> int {
        const int w = kk >> 6;
        const unsigned long long m = neg ? sel4(FNn0, FNn1, FNn2, FNn3, w)
                                         : sel4(FNp0, FNp1, FNp2, FNp3, w);
        return (int)((m >> (kk & 63)) & 1ull);
    };

    // ---- serial state ----
    int k = 0, k0 = 0, km = 0, kp = 0;
    float umin = lam, umax = mlam;
    const float v0 = rlane(v.r0, 0);
    float vmin = v0 - lam, vmax = v0 + lam;
    float flen = 1.0f;                  // = k - k0 + 1
    float rnext = 0.5f;                 // invariant: rnext == rcp(flen + 1)
    float vn1 = rlane(vnx.r0, 0);       // v[k+1]

    // pre: standard-fresh at k (=k0=km=kp), next jump forced, k <= N-2.
    // EXIT direction = sign(d[k]) is looked up here (NOT the entry direction).
    auto fastfwd = [&]() {
        const int K1 = firstnf(k + 1);                        // first non-forced j > k (<= 255)
        const int sneg = (int)((sel4(S0, S1, S2, S3, k >> 6) >> (k & 63)) & 1ull); // sign(d[k])
        flushseg(o, k, k, sneg ? vmin : vmax, lane);          // first run element
        if (K1 > k + 1) {                                     // (k, K1-1]: closed-form e[j]
            const int lo = k + 1;
            const unsigned len = (unsigned)(K1 - 1 - lo);
            const int base = lane - lo;
            o.r0 = ((unsigned)(base      ) <= len) ? e.r0 : o.r0;
            o.r1 = ((unsigned)(base + 64 ) <= len) ? e.r1 : o.r1;
            o.r2 = ((unsigned)(base + 128) <= len) ? e.r2 : o.r2;
            o.r3 = ((unsigned)(base + 192) <= len) ? e.r3 : o.r3;
        }
        k = K1; k0 = K1; km = K1; kp = K1;                    // fresh at K1, entry sign = S[K1-1]
        vmin = dfetch(g, K1);                                 // = v[K1] - lam - sl[K1-1]
        vmax = vmin + twolam;
        umin = lam; umax = mlam;
        flen = 1.0f; rnext = 0.5f;
        vn1 = dfetch(vnx, K1);                                // shares lane/sel calc with g fetch
    };

    auto do_step = [&]() {
        const float un = umin + vn1 - vmin;
        const float ux = umax + vn1 - vmax;
        const bool neg = un < mlam;
        const bool pos = ux > lam;
        // speculative FF-trigger bits for the fresh landing spot k+1 (off-chain SALU)
        const int wn = (k + 1) >> 6, bn = (k + 1) & 63;
        const int tn = (int)((sel4(FNn0, FNn1, FNn2, FNn3, wn) >> bn) & 1ull);
        const int tp = (int)((sel4(FNp0, FNp1, FNp2, FNp3, wn) >> bn) & 1ull);
        if (__builtin_expect((int)(neg | pos), 1)) {          // JUMP
            const float fval = neg ? vmin : vmax;
            const int   fhi  = neg ? km : kp;
            flushseg(o, k0, fhi, fval, lane);
            const int k0n = fhi + 1;
            float vstar;
            int trig;
            if (__builtin_expect((int)(k0n <= k), 0)) {       // rewind (rare)
                vstar = dfetch(v, k0n);
                trig = trigbit(k0n, (int)neg);
            } else {                                          // fresh: renames + precomputed trig
                vstar = vn1;
                trig = neg ? tn : tp;
            }
            k = k0n; k0 = k0n; km = k0n; kp = k0n;
            vmin = neg ? vstar : vstar - twolam;
            vmax = vmin + twolam;
            umin = lam; umax = mlam;
            flen = 1.0f; rnext = 0.5f;
            if (k < N - 1 && trig) {
                fastfwd();                                    // run of guaranteed jumps
            } else {
                vn1 = dfetch(vnx, k);                         // = v[k+1] (total, clamp-free)
            }
        } else {                                              // no jump (predicated)
            k++;
            const float r = rnext;                            // = rcp(k - k0 + 1), precomputed
            flen += 1.0f;
            const bool cmin = (un >= lam);
            const bool cmax = (ux <= mlam);
            vmin = cmin ? fmaf(un - lam, r, vmin) : vmin;
            km   = cmin ? k : km;
            umin = cmin ? lam : un;
            vmax = cmax ? fmaf(ux + lam, r, vmax) : vmax;
            kp   = cmax ? k : kp;
            umax = cmax ? mlam : ux;
            vn1 = dfetch(vnx, k);                             // = v[k+1] (total, clamp-free)
            rnext = __builtin_amdgcn_rcpf(flen + 1.0f);       // off-chain for next step
        }
    };

    if (initFF) fastfwd();

    for (;;) {
        while (k < N - 1) {
            do_step();
            if (k >= N - 1) break;
            do_step();
        }
        // boundary resolution at k == N-1 (verbatim semantics from verified R2/R6)
        for (;;) {
            if (umin < 0.0f) {
                flushseg(o, k0, km, vmin, lane);
                k0 = km + 1;
                if (k0 > N - 1) return;
                km = k = k0;
                vmin = dfetch(v, k0);
                umin = lam;
                umax = vmin + lam - vmax;
                flen = 1.0f;
            } else if (umax > 0.0f) {
                flushseg(o, k0, kp, vmax, lane);
                k0 = kp + 1;
                if (k0 > N - 1) return;
                kp = k = k0;
                vmax = dfetch(v, k0);
                umax = mlam;
                umin = vmax - lam - vmin;
                flen = 1.0f;
            } else {
                vmin += umin / flen;
                flushseg(o, k0, k, vmin, lane);
                return;
            }
            if (k != N - 1) break;
        }
        rnext = 0.5f;                                         // flen == 1 here
        vn1 = dfetch(vnx, k);                                 // = v[k+1]
    }
}

// Per-WAVE grid barrier over L2-bypassing flag slots (one slot per LINE; block ==
// one wave, so there is NO intra-block sync anywhere). Arrive: s_waitcnt drains
// the wave's own coalesced data stores, then store {payload,seq}. Poll: 4 slots
// per lane, software-pipelined (probe n+1 issues before probe n's ballot
// resolves). Release: poll exit itself — no relay.
// Payload-carry invariant (max skew 1, same argument as the block version): for
// any wave to store seq+2 it must first observe ALL slots >= seq+1; while any
// wave still polls seq, no slot can exceed seq+1, and the seq+1 payload
// (accprev) equals the seq payload by construction. Grid-max over observed
// payloads is therefore exact and identical across waves.
template <bool WANT>
__device__ __forceinline__ unsigned wavebar(unsigned long long* slots, unsigned seq,
                                            unsigned payload, int line, int lane)
{
    __builtin_amdgcn_s_waitcnt(0);                            // own data stores drained
    __hip_atomic_store(&slots[line * SLOTSTRIDE],
                       ((unsigned long long)payload << 32) | (unsigned long long)seq,
                       __ATOMIC_RELAXED, __HIP_MEMORY_SCOPE_AGENT);
    auto ld = [&](int i) {
        return __hip_atomic_load(&slots[i * SLOTSTRIDE],
                                 __ATOMIC_RELAXED, __HIP_MEMORY_SCOPE_AGENT);
    };
    unsigned long long f0 = ld(lane), f1 = ld(lane + 64),
                       f2 = ld(lane + 128), f3 = ld(lane + 192);
    for (;;) {
        unsigned long long g0 = ld(lane), g1 = ld(lane + 64),
                           g2 = ld(lane + 128), g3 = ld(lane + 192);
        const bool ok = ((unsigned)f0 >= seq) & ((unsigned)f1 >= seq) &
                        ((unsigned)f2 >= seq) & ((unsigned)f3 >= seq);
        if (__all((int)ok)) break;
        f0 = g0; f1 = g1; f2 = g2; f3 = g3;
    }
    unsigned ga = 0u;
    if (WANT) {                                               // grid-max of payloads, in-poll
        unsigned a = (unsigned)(f0 >> 32), b = (unsigned)(f1 >> 32);
        unsigned c = (unsigned)(f2 >> 32), d = (unsigned)(f3 >> 32);
        a = a > b ? a : b;  c = c > d ? c : d;  a = a > c ? a : c;
        ga = wredmax(a);                                      // uint order == float order (acc>=0)
    }
    return ga;
}

// Douglas-Rachford TV2D, one wave per line, one block per CU. The matrix
// transpose between phases happens entirely in L3: every phase WRITES its
// result coalesced (row of the consumer-agnostic row-major buffer) and READS
// its input as a scattered column (4 stride-1KB dword loads, one round trip).
// No LDS, no __syncthreads anywhere.
__global__ __launch_bounds__(NT) void tv2d_coop(const float* __restrict__ X,
                                                float* __restrict__ xw,     // = d_out (row-major x2)
                                                float* __restrict__ yt,     // yT: yt[c][j] = y[j][c]
                                                unsigned long long* __restrict__ slots)
{
    const int lane = threadIdx.x;
    const int b = blockIdx.x;                    // owned column (phase 1) / row (phase 2)

    Dist p = {0.f, 0.f, 0.f, 0.f};
    Dist q = {0.f, 0.f, 0.f, 0.f};
    unsigned accprev = 0u;                       // this wave's acc from previous iteration

    for (int it = 0; it < MAXIT; ++it) {
        // ---- column phase: y[:,b] = prox(x[:,b] + p); p = v - y ----
        const float* xs = (it == 0) ? X : xw;    // both row-major; column read is scattered
        Dist v, o;
        gload_col(xs, b, lane, v.r0, v.r1, v.r2, v.r3);
        v.r0 += p.r0;  v.r1 += p.r1;  v.r2 += p.r2;  v.r3 += p.r3;
        tv1d_scan(v, o, lane);
        p.r0 = v.r0 - o.r0;  p.r1 = v.r1 - o.r1;
        p.r2 = v.r2 - o.r2;  p.r3 = v.r3 - o.r3;
        float* yr = yt + b * N;                  // yT row b (coalesced): yt[b][j] = y[j][b]
        gstore(yr + lane,       o.r0);
        gstore(yr + lane + 64,  o.r1);
        gstore(yr + lane + 128, o.r2);
        gstore(yr + lane + 192, o.r3);
        wavebar<false>(slots, 2u * (unsigned)it + 1u, accprev, b, lane);

        // ---- row phase: x2[b,:] = prox(y[b,:] + q); q = w - x2; acc = max|y-x2| ----
        Dist yv, w, o2;
        gload_col(yt, b, lane, yv.r0, yv.r1, yv.r2, yv.r3);   // y[b][j] = yt[j][b] (scattered)
        w.r0 = yv.r0 + q.r0;
        w.r1 = yv.r1 + q.r1;
        w.r2 = yv.r2 + q.r2;
        w.r3 = yv.r3 + q.r3;
        tv1d_scan(w, o2, lane);
        float d0 = yv.r0 - o2.r0;    // y - x2
        float d1 = yv.r1 - o2.r1;
        float d2 = yv.r2 - o2.r2;
        float d3 = yv.r3 - o2.r3;
        q.r0 = w.r0 - o2.r0;  q.r1 = w.r1 - o2.r1;
        q.r2 = w.r2 - o2.r2;  q.r3 = w.r3 - o2.r3;
        float* xr = xw + b * N;                  // row-major output row (coalesced)
        gstore(xr + lane,       o2.r0);
        gstore(xr + lane + 64,  o2.r1);
        gstore(xr + lane + 128, o2.r2);
        gstore(xr + lane + 192, o2.r3);

        float am = fmaxf(fmaxf(fabsf(d0), fabsf(d1)), fmaxf(fabsf(d2), fabsf(d3)));
        const unsigned amu = wredmax(__float_as_uint(am));    // wave max via DPP ladder

        if (it == MAXIT - 1) break;              // nothing after the last row phase is read

        // ---- barrier 2: packed {acc, seq}; grid-max decision computed in-poll ----
        const unsigned ga = wavebar<true>(slots, 2u * (unsigned)it + 2u, amu, b, lane);
        if (__uint_as_float(ga) < TOL) break;    // xw holds x2 of `it` (reference output)
        accprev = amu;
    }
}

extern "C" void kernel_launch(void* const* d_in, const int* in_sizes, int n_in,
                              void* d_out, int out_size, void* d_ws, size_t ws_size,
                              hipStream_t stream) {
    const float* X = (const float*)d_in[0];
    float* xw = (float*)d_out;
    float* yt = (float*)d_ws;
    unsigned long long* slots = (unsigned long long*)((char*)d_ws + (size_t)N * N * sizeof(float));
    // zero the slot array (256 slots x 16 B = 4 KB) before the kernel (capture-legal)
    (void)hipMemsetAsync((void*)slots, 0, N * SLOTSTRIDE * sizeof(unsigned long long), stream);
    void* args[] = { (void*)&X, (void*)&xw, (void*)&yt, (void*)&slots };
    (void)hipLaunchCooperativeKernel((void*)tv2d_coop, dim3(NB), dim3(NT), args, 0, stream);
}